// Round 13
// baseline (3685.663 us; speedup 1.0000x reference)
//
#include <hip/hip_runtime.h>
#include <cfloat>

// Problem constants (fixed by setup_inputs)
#define BATCH 128
#define NP    16384
#define NC    4096
#define MPTS  (NP + NC)   // 20480
#define SOUT  2048
#define NTHR  1024
#define KPT   20          // points per thread, CONTIGUOUS: m = t*KPT + k
#define NPAIR (KPT / 2)
#define NWAVE (NTHR / 64)

// Packed fp32 (CDNA VOP3P): 2 points per instruction. Per-half IEEE
// semantics identical to the scalar path — proven bit-exact in round 4.
__device__ __forceinline__ float2 pk_add(float2 a, float2 b) {
    float2 d; asm("v_pk_add_f32 %0, %1, %2" : "=v"(d) : "v"(a), "v"(b)); return d;
}
__device__ __forceinline__ float2 pk_mul(float2 a, float2 b) {
    float2 d; asm("v_pk_mul_f32 %0, %1, %2" : "=v"(d) : "v"(a), "v"(b)); return d;
}
__device__ __forceinline__ float2 pk_fma(float2 a, float2 b, float2 c) {
    float2 d; asm("v_pk_fma_f32 %0, %1, %2, %3" : "=v"(d) : "v"(a), "v"(b), "v"(c)); return d;
}

// One f32 DPP max step. old=0 / bound_ctrl=false: lanes with invalid source
// (or masked rows) contribute 0.0f, the identity for max over md >= 0.
#define DPP_MAXF_STEP(ctrl, rmask)                                                 \
    {                                                                              \
        const unsigned int o = (unsigned int)__builtin_amdgcn_update_dpp(          \
            0, (int)__float_as_uint(wv), (ctrl), (rmask), 0xF, false);             \
        wv = fmaxf(wv, __uint_as_float(o));                                        \
    }

// One block per batch (128 blocks, 16 waves). Each thread owns 20 CONTIGUOUS
// points m = t*20+k; coords as float2 pairs (k=2p, 2p+1), min-distances as
// scalars. Per step:
//   phase A: packed distance update (pk_add/pk_mul/pk_fma per reference
//            contraction fma(dz,dz, fma(dx,dx, rn(dy*dy)))), scalar fminf,
//            v_max3 running max; 6-step f32 DPP wave max -> s_val[wid];
//   phase B: block max over 16 broadcast floats; candidate threads scan md
//            for the first k and atomicMin the GLOBAL index (contiguous
//            ownership => (t,k) order == m order, exact first-index ties);
//            winner coords reloaded from global at a uniform L2-hot address.
__global__ __launch_bounds__(NTHR)
__attribute__((amdgpu_waves_per_eu(4, 4)))
void fps_kernel(
    const float* __restrict__ partial,   // [B, NP, 3]
    const float* __restrict__ coarse,    // [B, 3, NC]
    float* __restrict__ out)             // [B, 3, SOUT]
{
    const int b = blockIdx.x;
    const int t = threadIdx.x;
    const int wid = t >> 6;
    const int lane = t & 63;

    __shared__ __align__(16) float s_val[NWAVE];  // per-wave max values
    __shared__ unsigned int s_mi[2];              // double-buffered argmin-index

    float2 x2[NPAIR], y2[NPAIR], z2[NPAIR];
    float md[KPT];

    const float* Pb = partial + (size_t)b * NP * 3;
    const float* Cb = coarse + (size_t)b * 3 * NC;

#pragma unroll
    for (int p = 0; p < NPAIR; ++p) {
        const int m0 = t * KPT + 2 * p;       // contiguous ownership
        const int m1 = m0 + 1;
        float c0[3], c1[3];
        if (m0 < NP) {
            c0[0] = Pb[(size_t)m0 * 3 + 0];
            c0[1] = Pb[(size_t)m0 * 3 + 1];
            c0[2] = Pb[(size_t)m0 * 3 + 2];
        } else {
            const int j = m0 - NP;
            c0[0] = Cb[0 * NC + j]; c0[1] = Cb[1 * NC + j]; c0[2] = Cb[2 * NC + j];
        }
        if (m1 < NP) {
            c1[0] = Pb[(size_t)m1 * 3 + 0];
            c1[1] = Pb[(size_t)m1 * 3 + 1];
            c1[2] = Pb[(size_t)m1 * 3 + 2];
        } else {
            const int j = m1 - NP;
            c1[0] = Cb[0 * NC + j]; c1[1] = Cb[1 * NC + j]; c1[2] = Cb[2 * NC + j];
        }
        x2[p].x = c0[0]; x2[p].y = c1[0];
        y2[p].x = c0[1]; y2[p].y = c1[1];
        z2[p].x = c0[2]; z2[p].y = c1[2];
        md[2 * p] = FLT_MAX; md[2 * p + 1] = FLT_MAX;
    }

    float* outb = out + (size_t)b * 3 * SOUT;

    // First selected index is 0: uniform read of its coords (L2-resident).
    float qx = Pb[0], qy = Pb[1], qz = Pb[2];
    if (t == 0) {
        outb[0 * SOUT + 0] = qx;
        outb[1 * SOUT + 0] = qy;
        outb[2 * SOUT + 0] = qz;
        s_mi[0] = 0xFFFFFFFFu;
        s_mi[1] = 0xFFFFFFFFu;
    }
    __syncthreads();

    for (int s = 0; s < SOUT - 1; ++s) {
        const int cur = s & 1, nxt = cur ^ 1;

        // Pin the point state for this iteration (emits no instructions;
        // blocks rematerialization). float2 pins are 64-bit "+v" pairs.
#pragma unroll
        for (int p = 0; p < NPAIR; ++p) {
            asm volatile("" : "+v"(x2[p]), "+v"(y2[p]), "+v"(z2[p]),
                             "+v"(md[2 * p]), "+v"(md[2 * p + 1]));
        }

        // Negated q: x + (-q) is bit-identical to x - q (round 4 proven).
        const float2 nq_x = {-qx, -qx}, nq_y = {-qy, -qy}, nq_z = {-qz, -qz};

        // ---- phase A: packed distance update, scalar min, running max ----
        float bv = 0.0f;   // md >= 0 always, so 0 is a safe identity
#pragma unroll
        for (int p = 0; p < NPAIR; ++p) {
            const float2 dx  = pk_add(x2[p], nq_x);
            const float2 dy  = pk_add(y2[p], nq_y);
            const float2 dz  = pk_add(z2[p], nq_z);
            const float2 dy2 = pk_mul(dy, dy);
            const float2 ts  = pk_fma(dx, dx, dy2);
            const float2 dd  = pk_fma(dz, dz, ts);
            // Per-half: fma(dz,dz, fma(dx,dx, rn(dy*dy))) — reference-exact.
            const float n0 = fminf(md[2 * p], dd.x);
            const float n1 = fminf(md[2 * p + 1], dd.y);
            md[2 * p] = n0;
            md[2 * p + 1] = n1;
            bv = fmaxf(fmaxf(bv, n0), n1);   // fuses to v_max3_f32
        }

        // Wave max to lane 63 (canonical gfx9 pattern, f32).
        float wv = bv;
        DPP_MAXF_STEP(0x111, 0xF)  // row_shr:1
        DPP_MAXF_STEP(0x112, 0xF)  // row_shr:2
        DPP_MAXF_STEP(0x114, 0xF)  // row_shr:4
        DPP_MAXF_STEP(0x118, 0xF)  // row_shr:8
        DPP_MAXF_STEP(0x142, 0xa)  // row_bcast:15
        DPP_MAXF_STEP(0x143, 0xc)  // row_bcast:31

        if (lane == 63) s_val[wid] = wv;
        if (t == 0) s_mi[nxt] = 0xFFFFFFFFu;   // reset other slot for step s+1
        __syncthreads();

        // ---- phase B: block max (broadcast reads), index resolution ----
        const float4* sv4 = (const float4*)s_val;
        const float4 v0 = sv4[0], v1 = sv4[1], v2 = sv4[2], v3 = sv4[3];
        float bvmax = fmaxf(fmaxf(fmaxf(v0.x, v0.y), fmaxf(v0.z, v0.w)),
                            fmaxf(fmaxf(v1.x, v1.y), fmaxf(v1.z, v1.w)));
        bvmax = fmaxf(bvmax,
                      fmaxf(fmaxf(fmaxf(v2.x, v2.y), fmaxf(v2.z, v2.w)),
                            fmaxf(fmaxf(v3.x, v3.y), fmaxf(v3.z, v3.w))));

        if (bv == bvmax) {
            // First k with md[k]==bvmax (descending overwrite keeps smallest).
            int kf = 0;
#pragma unroll
            for (int k = KPT - 1; k >= 0; --k) {
                if (md[k] == bvmax) kf = k;
            }
            atomicMin(&s_mi[cur], (unsigned int)(t * KPT + kf));
        }
        __syncthreads();

        const unsigned int m = s_mi[cur];   // global winner index (uniform)

        // Reload winner coords from global: uniform address -> one L2-hot
        // broadcast per wave; bit-exact same values as the owner's registers.
        if (m < NP) {
            const float* p = Pb + (size_t)m * 3;
            qx = p[0]; qy = p[1]; qz = p[2];
        } else {
            const int j = (int)m - NP;
            qx = Cb[0 * NC + j];
            qy = Cb[1 * NC + j];
            qz = Cb[2 * NC + j];
        }

        if (t == 0) {
            const int slot = s + 1;
            outb[0 * SOUT + slot] = qx;
            outb[1 * SOUT + slot] = qy;
            outb[2 * SOUT + slot] = qz;
        }
        // s_val WAR across steps is safe: step s+1's writes happen after
        // this step's second barrier; step s's reads happened before it.
    }
}

extern "C" void kernel_launch(void* const* d_in, const int* in_sizes, int n_in,
                              void* d_out, int out_size, void* d_ws, size_t ws_size,
                              hipStream_t stream) {
    (void)in_sizes; (void)n_in; (void)d_ws; (void)ws_size; (void)out_size;
    const float* partial = (const float*)d_in[0];
    const float* coarse  = (const float*)d_in[1];
    float* out = (float*)d_out;
    fps_kernel<<<dim3(BATCH), dim3(NTHR), 0, stream>>>(partial, coarse, out);
}